// Round 4
// baseline (1109.278 us; speedup 1.0000x reference)
//
#include <hip/hip_runtime.h>
#include <math.h>

// Llama4TextMoe — bf16 MFMA, round 4: corrected ds_read_b64_tr_b16 B-path.
// tr_b16 decode (m156+m162 consistent): byte addr A -> elem j at
//   (A & ~127) + 2*((A>>3)&15) + 32*j   (128B block = 4x16 row-major bf16 tile,
//   lane reads column (A>>3)&15). So: tiles must be 128B-aligned 128B blocks;
//   lane addr = tile_base + 8*(lane&15); offset: immediates multiples of 128.
// B LDS: per matrix 8 nblk x 8 kblk x 128B tiles (nblk-outer = 8x[32k][16n]),
//   tile row-major (k&3)*32 + (n&15)*2. Staging: k=(s&3)|((s>>7)<<2),
//   nq=(s>>2)&31 -> coalesced float4 loads (4 rows x 256B) + 4-way write banks.
// A-path / epilogues / bookkeeping = round-2-validated.

#define BM 128
#define BN 128
#define BK 32
#define LDPA 40      // A row pitch (bf16 elems)
#define MAXT 32
#define BMAT 8192    // bytes per B matrix in LDS (8 nblk * 8 kblk * 128B)

typedef float f32x4 __attribute__((ext_vector_type(4)));
typedef short bf16x8 __attribute__((ext_vector_type(8)));
typedef short bf16x4 __attribute__((ext_vector_type(4)));
typedef __bf16 bf2 __attribute__((ext_vector_type(2)));

union B8 { bf16x8 v; struct { bf16x4 lo, hi; } h; };

__device__ inline unsigned int pk2(float a, float b) {
    union { bf2 h; unsigned int u; } c;
    c.h[0] = (__bf16)a; c.h[1] = (__bf16)b;   // v_cvt_pk_bf16_f32
    return c.u;
}
__device__ inline unsigned long long pk4(float4 v) {
    return (unsigned long long)pk2(v.x, v.y) | ((unsigned long long)pk2(v.z, v.w) << 32);
}
__device__ inline unsigned short f2bf(float a) {
    union { __bf16 h; unsigned short u; } c; c.h = (__bf16)a; return c.u;
}
__device__ inline bf16x8 pk8(float4 a, float4 b) {
    union { bf16x8 v; unsigned int u[4]; } c;
    c.u[0] = pk2(a.x, a.y); c.u[1] = pk2(a.z, a.w);
    c.u[2] = pk2(b.x, b.y); c.u[3] = pk2(b.z, b.w);
    return c.v;
}

// two transpose-reads -> one bf16x8 frag: elem j = B[8*(lane>>4)+j][nblk*16+(lane&15)]
// earlyclobber: instr 1 writes %0 while %2 still needed by instr 2.
#define TR8(U, ADDR, IMM0, IMM1) \
    asm volatile("ds_read_b64_tr_b16 %0, %2 offset:" IMM0 "\n\t" \
                 "ds_read_b64_tr_b16 %1, %2 offset:" IMM1 \
                 : "=&v"((U).h.lo), "=&v"((U).h.hi) : "v"(ADDR))

#define LGKM_FENCE() do { \
    asm volatile("s_waitcnt lgkmcnt(0)" ::: "memory"); \
    __builtin_amdgcn_sched_barrier(0); } while (0)

// B staging slot for flat index s (0..1023): thread writes 4 n-consecutive elems of row k.
__device__ inline void b_slot(int s, int* k, int* nq, int* off) {
    *k  = (s & 3) | ((s >> 7) << 2);
    *nq = (s >> 2) & 31;
    *off = ((*nq) >> 2) * 1024 + (s >> 7) * 128 + (s & 3) * 32 + ((*nq) & 3) * 8;
}

// ---------------- router / bookkeeping (unchanged, validated) ----------------

__global__ __launch_bounds__(256) void router_kernel(
    const float* __restrict__ x, const float* __restrict__ rw,
    float* __restrict__ scores_out, int* __restrict__ eidx,
    float* __restrict__ score, int* __restrict__ counts, int T, int H, int E)
{
    int g = blockIdx.x * 256 + threadIdx.x;
    int t = g >> 3, e = g & 7;          // E == 8
    if (t >= T) return;
    const float* xr = x + (size_t)t * H;
    float acc = 0.f;
    for (int k = 0; k < H; k++) acc = fmaf(xr[k], rw[k * E + e], acc);
    float bv = acc; int bi = e;
    #pragma unroll
    for (int off = 4; off; off >>= 1) {
        float ov = __shfl_xor(bv, off, 8);
        int   oi = __shfl_xor(bi, off, 8);
        if (ov > bv || (ov == bv && oi < bi)) { bv = ov; bi = oi; }
    }
    float sig = 1.f / (1.f + __expf(-bv));
    scores_out[(size_t)e * T + t] = (e == bi) ? sig : 0.f;
    if (e == 0) {
        eidx[t] = bi;
        score[t] = sig;
        atomicAdd(&counts[bi], 1);
    }
}

__global__ void prefix_kernel(const int* __restrict__ counts, int* __restrict__ offs,
                              int* __restrict__ tile_e, int* __restrict__ tile_m,
                              int* __restrict__ ntile, int E)
{
    if (blockIdx.x == 0 && threadIdx.x == 0) {
        int run = 0, nt = 0;
        for (int e = 0; e < E; e++) {
            offs[e] = run;
            int c = counts[e];
            int t = (c + BM - 1) / BM;
            for (int i = 0; i < t; i++) { tile_e[nt] = e; tile_m[nt] = i * BM; nt++; }
            run += t * BM;
        }
        ntile[0] = nt;
    }
}

__global__ __launch_bounds__(256) void scatter_kernel(
    const int* __restrict__ eidx, const int* __restrict__ offs,
    int* __restrict__ cursor, int* __restrict__ list, int T)
{
    int t = blockIdx.x * 256 + threadIdx.x;
    if (t >= T) return;
    int e = eidx[t];
    int pos = offs[e] + atomicAdd(&cursor[e], 1);
    list[pos] = t;
}

// ---------------- shared expert up (gate+up, fused SwiGLU) ----------------

__global__ __launch_bounds__(256, 2) void shared_up(
    const float* __restrict__ X, const float* __restrict__ Wg,
    const float* __restrict__ Wu, unsigned short* __restrict__ Hout,
    int H, int I)
{
    __shared__ __attribute__((aligned(16)))  short As[BM][LDPA];
    __shared__ __attribute__((aligned(128))) char Bsh[2 * BMAT];
    const int tid = threadIdx.x;
    const int lane = tid & 63, wid = tid >> 6;
    const int wr = wid >> 1, wc = wid & 1;
    const int m0 = blockIdx.y * BM, n0 = blockIdx.x * BN;

    // A: thread -> row tid>>1, 16-k half (tid&1); 64B contiguous load
    const int am = tid >> 1, ak = (tid & 1) * 16;
    const float* apA = X + (size_t)(m0 + am) * H + ak;
    short* adst = &As[am][ak];

    char* bgd[4];
    const float *gsrc[4], *usrc[4];
#pragma unroll
    for (int p = 0; p < 4; p++) {
        int k, nq, off;
        b_slot(tid + p * 256, &k, &nq, &off);
        bgd[p] = Bsh + off;
        gsrc[p] = Wg + (size_t)k * I + (n0 + 4 * nq);
        usrc[p] = Wu + (size_t)k * I + (n0 + 4 * nq);
    }
    const int btr = (int)(size_t)Bsh + wc * 4096 + (lane >> 4) * 256 + 8 * (lane & 15);

    f32x4 accg[4][4], accu[4][4];
#pragma unroll
    for (int i = 0; i < 4; i++)
#pragma unroll
        for (int j = 0; j < 4; j++) {
            accg[i][j] = (f32x4){0.f, 0.f, 0.f, 0.f};
            accu[i][j] = (f32x4){0.f, 0.f, 0.f, 0.f};
        }

    float4 va[4], vg[4], vu[4];
#pragma unroll
    for (int q = 0; q < 4; q++) va[q] = *(const float4*)(apA + q * 4);
#pragma unroll
    for (int p = 0; p < 4; p++) { vg[p] = *(const float4*)gsrc[p]; vu[p] = *(const float4*)usrc[p]; }

    const int nK = H / BK;
    const int kh = (lane >> 4) * 8;
    for (int kt = 0; kt < nK; kt++) {
        __syncthreads();
        *(bf16x8*)adst       = pk8(va[0], va[1]);
        *(bf16x8*)(adst + 8) = pk8(va[2], va[3]);
#pragma unroll
        for (int p = 0; p < 4; p++) {
            *(unsigned long long*)bgd[p]          = pk4(vg[p]);
            *(unsigned long long*)(bgd[p] + BMAT) = pk4(vu[p]);
        }
        __syncthreads();
        if (kt + 1 < nK) {
            const int k0 = (kt + 1) * BK;
#pragma unroll
            for (int q = 0; q < 4; q++) va[q] = *(const float4*)(apA + k0 + q * 4);
#pragma unroll
            for (int p = 0; p < 4; p++) {
                vg[p] = *(const float4*)(gsrc[p] + (size_t)k0 * I);
                vu[p] = *(const float4*)(usrc[p] + (size_t)k0 * I);
            }
        }
        bf16x8 af[4];
#pragma unroll
        for (int q = 0; q < 4; q++)
            af[q] = *(const bf16x8*)&As[wr * 64 + q * 16 + (lane & 15)][kh];
        B8 gf[4], uf[4];
        TR8(gf[0], btr, "0",     "128");
        TR8(gf[1], btr, "1024",  "1152");
        TR8(gf[2], btr, "2048",  "2176");
        TR8(gf[3], btr, "3072",  "3200");
        TR8(uf[0], btr, "8192",  "8320");
        TR8(uf[1], btr, "9216",  "9344");
        TR8(uf[2], btr, "10240", "10368");
        TR8(uf[3], btr, "11264", "11392");
        LGKM_FENCE();
#pragma unroll
        for (int mi = 0; mi < 4; mi++)
#pragma unroll
            for (int nj = 0; nj < 4; nj++) {
                accg[mi][nj] = __builtin_amdgcn_mfma_f32_16x16x32_bf16(af[mi], gf[nj].v, accg[mi][nj], 0, 0, 0);
                accu[mi][nj] = __builtin_amdgcn_mfma_f32_16x16x32_bf16(af[mi], uf[nj].v, accu[mi][nj], 0, 0, 0);
            }
    }

    const int rb = (lane >> 4) * 4, cb = lane & 15;
#pragma unroll
    for (int mi = 0; mi < 4; mi++)
#pragma unroll
        for (int nj = 0; nj < 4; nj++) {
            int col = n0 + wc * 64 + nj * 16 + cb;
#pragma unroll
            for (int j = 0; j < 4; j++) {
                float g = accg[mi][nj][j], u = accu[mi][nj][j];
                float r = u * g * __builtin_amdgcn_rcpf(1.f + __expf(-g));
                int row = m0 + wr * 64 + mi * 16 + rb + j;
                Hout[(size_t)row * I + col] = f2bf(r);
            }
        }
}

// ---------------- routed experts up (gathered + score-scaled A) ----------------

__global__ __launch_bounds__(256, 2) void routed_up(
    const float* __restrict__ X, const float* __restrict__ GUP,
    const int* __restrict__ counts, const int* __restrict__ offs,
    const int* __restrict__ list, const float* __restrict__ score,
    const int* __restrict__ tile_e, const int* __restrict__ tile_m,
    const int* __restrict__ ntile,
    unsigned short* __restrict__ Hout, int H, int I)
{
    const int gt = blockIdx.y;
    if (gt >= ntile[0]) return;
    const int e = tile_e[gt], mbase = tile_m[gt];
    const int count = counts[e], off_e = offs[e];
    const float* W = GUP + (size_t)e * H * (2 * I);
    const size_t ldw = 2 * (size_t)I;

    __shared__ __attribute__((aligned(16)))  short As[BM][LDPA];
    __shared__ __attribute__((aligned(128))) char Bsh[2 * BMAT];
    const int tid = threadIdx.x;
    const int lane = tid & 63, wid = tid >> 6;
    const int wr = wid >> 1, wc = wid & 1;
    const int n0 = blockIdx.x * BN;

    const int am = tid >> 1, ak = (tid & 1) * 16;
    int gr = mbase + am;
    int tok = 0; float sA = 0.f;
    if (gr < count) { tok = list[off_e + gr]; sA = score[tok]; }
    const float* apA = X + (size_t)tok * H + ak;
    short* adst = &As[am][ak];

    char* bgd[4];
    const float *gsrc[4], *usrc[4];
#pragma unroll
    for (int p = 0; p < 4; p++) {
        int k, nq, off;
        b_slot(tid + p * 256, &k, &nq, &off);
        bgd[p] = Bsh + off;
        gsrc[p] = W + (size_t)k * ldw + (n0 + 4 * nq);
        usrc[p] = gsrc[p] + I;
    }
    const int btr = (int)(size_t)Bsh + wc * 4096 + (lane >> 4) * 256 + 8 * (lane & 15);

    f32x4 accg[4][4], accu[4][4];
#pragma unroll
    for (int i = 0; i < 4; i++)
#pragma unroll
        for (int j = 0; j < 4; j++) {
            accg[i][j] = (f32x4){0.f, 0.f, 0.f, 0.f};
            accu[i][j] = (f32x4){0.f, 0.f, 0.f, 0.f};
        }

    float4 va[4], vg[4], vu[4];
#pragma unroll
    for (int q = 0; q < 4; q++) va[q] = *(const float4*)(apA + q * 4);
#pragma unroll
    for (int p = 0; p < 4; p++) { vg[p] = *(const float4*)gsrc[p]; vu[p] = *(const float4*)usrc[p]; }

    const int nK = H / BK;
    const int kh = (lane >> 4) * 8;
    for (int kt = 0; kt < nK; kt++) {
        __syncthreads();
        {
            float4 s0 = make_float4(va[0].x * sA, va[0].y * sA, va[0].z * sA, va[0].w * sA);
            float4 s1 = make_float4(va[1].x * sA, va[1].y * sA, va[1].z * sA, va[1].w * sA);
            float4 s2 = make_float4(va[2].x * sA, va[2].y * sA, va[2].z * sA, va[2].w * sA);
            float4 s3 = make_float4(va[3].x * sA, va[3].y * sA, va[3].z * sA, va[3].w * sA);
            *(bf16x8*)adst       = pk8(s0, s1);
            *(bf16x8*)(adst + 8) = pk8(s2, s3);
        }
#pragma unroll
        for (int p = 0; p < 4; p++) {
            *(unsigned long long*)bgd[p]          = pk4(vg[p]);
            *(unsigned long long*)(bgd[p] + BMAT) = pk4(vu[p]);
        }
        __syncthreads();
        if (kt + 1 < nK) {
            const int k0 = (kt + 1) * BK;
#pragma unroll
            for (int q = 0; q < 4; q++) va[q] = *(const float4*)(apA + k0 + q * 4);
#pragma unroll
            for (int p = 0; p < 4; p++) {
                vg[p] = *(const float4*)(gsrc[p] + (size_t)k0 * ldw);
                vu[p] = *(const float4*)(usrc[p] + (size_t)k0 * ldw);
            }
        }
        bf16x8 af[4];
#pragma unroll
        for (int q = 0; q < 4; q++)
            af[q] = *(const bf16x8*)&As[wr * 64 + q * 16 + (lane & 15)][kh];
        B8 gf[4], uf[4];
        TR8(gf[0], btr, "0",     "128");
        TR8(gf[1], btr, "1024",  "1152");
        TR8(gf[2], btr, "2048",  "2176");
        TR8(gf[3], btr, "3072",  "3200");
        TR8(uf[0], btr, "8192",  "8320");
        TR8(uf[1], btr, "9216",  "9344");
        TR8(uf[2], btr, "10240", "10368");
        TR8(uf[3], btr, "11264", "11392");
        LGKM_FENCE();
#pragma unroll
        for (int mi = 0; mi < 4; mi++)
#pragma unroll
            for (int nj = 0; nj < 4; nj++) {
                accg[mi][nj] = __builtin_amdgcn_mfma_f32_16x16x32_bf16(af[mi], gf[nj].v, accg[mi][nj], 0, 0, 0);
                accu[mi][nj] = __builtin_amdgcn_mfma_f32_16x16x32_bf16(af[mi], uf[nj].v, accu[mi][nj], 0, 0, 0);
            }
    }

    const int rb = (lane >> 4) * 4, cb = lane & 15;
#pragma unroll
    for (int mi = 0; mi < 4; mi++)
#pragma unroll
        for (int nj = 0; nj < 4; nj++) {
            int col = n0 + wc * 64 + nj * 16 + cb;
#pragma unroll
            for (int j = 0; j < 4; j++) {
                float g = accg[mi][nj][j], u = accu[mi][nj][j];
                float r = u * g * __builtin_amdgcn_rcpf(1.f + __expf(-g));
                int row = off_e + mbase + wr * 64 + mi * 16 + rb + j;
                Hout[(size_t)row * I + col] = f2bf(r);
            }
        }
}

// ---------------- fused down: out[tok] = SH[tok]@Wsd + RH[slot]@Dp_e ----------------

__global__ __launch_bounds__(256, 2) void fused_down(
    const unsigned short* __restrict__ SH, const unsigned short* __restrict__ RH,
    const float* __restrict__ Wsd, const float* __restrict__ DP,
    const int* __restrict__ counts, const int* __restrict__ offs,
    const int* __restrict__ list,
    const int* __restrict__ tile_e, const int* __restrict__ tile_m,
    const int* __restrict__ ntile,
    float* __restrict__ out, int I, int H)
{
    const int gt = blockIdx.y;
    if (gt >= ntile[0]) return;
    const int e = tile_e[gt], mbase = tile_m[gt];
    const int count = counts[e], off_e = offs[e];
    const float* W2 = DP + (size_t)e * I * H;

    __shared__ __attribute__((aligned(16)))  short A1[BM][LDPA], A2[BM][LDPA];
    __shared__ __attribute__((aligned(128))) char Bsh[2 * BMAT];
    __shared__ int toks[BM];
    const int tid = threadIdx.x;
    const int lane = tid & 63, wid = tid >> 6;
    const int wr = wid >> 1, wc = wid & 1;
    const int n0 = blockIdx.x * BN;

    if (tid < BM) {
        int gr = mbase + tid;
        toks[tid] = (gr < count) ? list[off_e + gr] : -1;
    }
    __syncthreads();

    const int am = tid >> 1, ak = (tid & 1) * 16;
    int tokA = toks[am]; if (tokA < 0) tokA = 0;
    const unsigned short* a1p = SH + (size_t)tokA * I + ak;
    const unsigned short* a2p = RH + (size_t)(off_e + mbase + am) * I + ak;
    short* a1d = &A1[am][ak];
    short* a2d = &A2[am][ak];

    char* b1d[4];
    const float *b1s[4], *b2s[4];
#pragma unroll
    for (int p = 0; p < 4; p++) {
        int k, nq, off;
        b_slot(tid + p * 256, &k, &nq, &off);
        b1d[p] = Bsh + off;
        b1s[p] = Wsd + (size_t)k * H + (n0 + 4 * nq);
        b2s[p] = W2  + (size_t)k * H + (n0 + 4 * nq);
    }
    const int btr = (int)(size_t)Bsh + wc * 4096 + (lane >> 4) * 256 + 8 * (lane & 15);

    f32x4 acc[4][4];
#pragma unroll
    for (int i = 0; i < 4; i++)
#pragma unroll
        for (int j = 0; j < 4; j++) acc[i][j] = (f32x4){0.f, 0.f, 0.f, 0.f};

    bf16x8 w1[2], w2[2];
    float4 vb1[4], vb2[4];
    w1[0] = *(const bf16x8*)a1p; w1[1] = *(const bf16x8*)(a1p + 8);
    w2[0] = *(const bf16x8*)a2p; w2[1] = *(const bf16x8*)(a2p + 8);
#pragma unroll
    for (int p = 0; p < 4; p++) { vb1[p] = *(const float4*)b1s[p]; vb2[p] = *(const float4*)b2s[p]; }

    const int nK = I / BK;
    const int kh = (lane >> 4) * 8;
    for (int kt = 0; kt < nK; kt++) {
        __syncthreads();
        *(bf16x8*)a1d       = w1[0];
        *(bf16x8*)(a1d + 8) = w1[1];
        *(bf16x8*)a2d       = w2[0];
        *(bf16x8*)(a2d + 8) = w2[1];
#pragma unroll
        for (int p = 0; p < 4; p++) {
            *(unsigned long long*)b1d[p]          = pk4(vb1[p]);
            *(unsigned long long*)(b1d[p] + BMAT) = pk4(vb2[p]);
        }
        __syncthreads();
        if (kt + 1 < nK) {
            const int k0 = (kt + 1) * BK;
            w1[0] = *(const bf16x8*)(a1p + k0); w1[1] = *(const bf16x8*)(a1p + k0 + 8);
            w2[0] = *(const bf16x8*)(a2p + k0); w2[1] = *(const bf16x8*)(a2p + k0 + 8);
#pragma unroll
            for (int p = 0; p < 4; p++) {
                vb1[p] = *(const float4*)(b1s[p] + (size_t)k0 * H);
                vb2[p] = *(const float4*)(b2s[p] + (size_t)k0 * H);
            }
        }
        bf16x8 af1[4], af2[4];
#pragma unroll
        for (int q = 0; q < 4; q++) {
            af1[q] = *(const bf16x8*)&A1[wr * 64 + q * 16 + (lane & 15)][kh];
            af2[q] = *(const bf16x8*)&A2[wr * 64 + q * 16 + (lane & 15)][kh];
        }
        B8 b1f[4], b2f[4];
        TR8(b1f[0], btr, "0",     "128");
        TR8(b1f[1], btr, "1024",  "1152");
        TR8(b1f[2], btr, "2048",  "2176");
        TR8(b1f[3], btr, "3072",  "3200");
        TR8(b2f[0], btr, "8192",  "8320");
        TR8(b2f[1], btr, "9216",  "9344");
        TR8(b2f[2], btr, "10240", "10368");
        TR8(b2f[3], btr, "11264", "11392");
        LGKM_FENCE();
#pragma unroll
        for (int mi = 0; mi < 4; mi++)
#pragma unroll
            for (int nj = 0; nj < 4; nj++) {
                acc[mi][nj] = __builtin_amdgcn_mfma_f32_16x16x32_bf16(af1[mi], b1f[nj].v, acc[mi][nj], 0, 0, 0);
                acc[mi][nj] = __builtin_amdgcn_mfma_f32_16x16x32_bf16(af2[mi], b2f[nj].v, acc[mi][nj], 0, 0, 0);
            }
    }

    const int rb = (lane >> 4) * 4, cb = lane & 15;
#pragma unroll
    for (int mi = 0; mi < 4; mi++)
#pragma unroll
        for (int nj = 0; nj < 4; nj++) {
            int col = n0 + wc * 64 + nj * 16 + cb;
#pragma unroll
            for (int j = 0; j < 4; j++) {
                int lr = wr * 64 + mi * 16 + rb + j;
                int tok = toks[lr];
                if (tok >= 0) out[(size_t)tok * H + col] = acc[mi][nj][j];
            }
        }
}

// ---------------- launcher ----------------

extern "C" void kernel_launch(void* const* d_in, const int* in_sizes, int n_in,
                              void* d_out, int out_size, void* d_ws, size_t ws_size,
                              hipStream_t stream)
{
    const float* x   = (const float*)d_in[0];
    const float* rw  = (const float*)d_in[1];
    const float* gup = (const float*)d_in[2];
    const float* dp  = (const float*)d_in[3];
    const float* sg  = (const float*)d_in[4];
    const float* su  = (const float*)d_in[5];
    const float* sd  = (const float*)d_in[6];

    const int H = 2048, I = 4096, E = 8;
    const int T = in_sizes[0] / H;            // 2048

    float* out        = (float*)d_out;
    float* scores_out = out + (size_t)T * H;  // router_scores [E, T]

    const int slotsCap = T + E * BM;          // 3072
    unsigned short* routedH = (unsigned short*)d_ws;                  // [slotsCap, I] bf16
    unsigned short* sharedH = routedH + (size_t)slotsCap * I;         // [T, I] bf16
    int*   list   = (int*)(sharedH + (size_t)T * I);                  // [slotsCap]
    int*   eidx   = list + slotsCap;                                  // [T]
    float* score  = (float*)(eidx + T);                               // [T]
    int*   counts = (int*)(score + T);                                // [E]
    int*   cursor = counts + E;                                       // [E]
    int*   offs   = cursor + E;                                       // [E]
    int*   ntile  = offs + E;                                         // [1]
    int*   tile_e = ntile + 1;                                        // [MAXT]
    int*   tile_m = tile_e + MAXT;                                    // [MAXT]

    const int maxTiles = T / BM + E;          // 24 (>= worst-case padded tile count)

    hipMemsetAsync(counts, 0, 2 * E * sizeof(int), stream);
    router_kernel<<<(T * E) / 256, 256, 0, stream>>>(x, rw, scores_out, eidx, score, counts, T, H, E);
    prefix_kernel<<<1, 1, 0, stream>>>(counts, offs, tile_e, tile_m, ntile, E);
    scatter_kernel<<<(T + 255) / 256, 256, 0, stream>>>(eidx, offs, cursor, list, T);
    shared_up<<<dim3(I / BN, T / BM), 256, 0, stream>>>(x, sg, su, sharedH, H, I);
    routed_up<<<dim3(I / BN, maxTiles), 256, 0, stream>>>(x, gup, counts, offs, list, score,
                                                          tile_e, tile_m, ntile, routedH, H, I);
    fused_down<<<dim3(H / BN, maxTiles), 256, 0, stream>>>(sharedH, routedH, sd, dp,
                                                           counts, offs, list,
                                                           tile_e, tile_m, ntile, out, I, H);
}

// Round 5
// 890.355 us; speedup vs baseline: 1.2459x; 1.2459x over previous
//
#include <hip/hip_runtime.h>
#include <math.h>

// Llama4TextMoe — bf16 MFMA, round 5: occupancy fix (BN 128->64).
// Round-4 lesson: grid ~270 blocks -> 1 wave/SIMD -> latency-bound (MfmaUtil 9.5%,
// VALU 4.6%, occ 10.9%). BN=64 doubles/quadruples blocks/CU (up: 1024 blocks = 4/CU,
// down: ~550 = 2-3/CU); LDS 18-29KB, VGPR ~110 -> 3-4 waves/SIMD co-resident to hide
// HBM prefetch latency + lgkm fence drains across waves.
// B-path (validated r4): fp32 [K,N] staged coalesced float4 -> cvt_pk -> b64 writes
// into 128B-aligned 4x16 tiles; frags via ds_read_b64_tr_b16
//   (byte addr A -> elem j at (A&~127) + 2*((A>>3)&15) + 32*j).

#define BM 128
#define BN 64
#define BK 32
#define LDPA 40      // A row pitch (bf16 elems)
#define MAXT 32
#define BMAT 4096    // bytes per B matrix in LDS (4 nblk * 8 kblk * 128B)

typedef float f32x4 __attribute__((ext_vector_type(4)));
typedef short bf16x8 __attribute__((ext_vector_type(8)));
typedef short bf16x4 __attribute__((ext_vector_type(4)));
typedef __bf16 bf2 __attribute__((ext_vector_type(2)));

union B8 { bf16x8 v; struct { bf16x4 lo, hi; } h; };

__device__ inline unsigned int pk2(float a, float b) {
    union { bf2 h; unsigned int u; } c;
    c.h[0] = (__bf16)a; c.h[1] = (__bf16)b;   // v_cvt_pk_bf16_f32
    return c.u;
}
__device__ inline unsigned long long pk4(float4 v) {
    return (unsigned long long)pk2(v.x, v.y) | ((unsigned long long)pk2(v.z, v.w) << 32);
}
__device__ inline unsigned short f2bf(float a) {
    union { __bf16 h; unsigned short u; } c; c.h = (__bf16)a; return c.u;
}
__device__ inline bf16x8 pk8(float4 a, float4 b) {
    union { bf16x8 v; unsigned int u[4]; } c;
    c.u[0] = pk2(a.x, a.y); c.u[1] = pk2(a.z, a.w);
    c.u[2] = pk2(b.x, b.y); c.u[3] = pk2(b.z, b.w);
    return c.v;
}

// two transpose-reads -> one bf16x8 frag: elem j = B[8*(lane>>4)+j][nblk*16+(lane&15)]
#define TR8(U, ADDR, IMM0, IMM1) \
    asm volatile("ds_read_b64_tr_b16 %0, %2 offset:" IMM0 "\n\t" \
                 "ds_read_b64_tr_b16 %1, %2 offset:" IMM1 \
                 : "=&v"((U).h.lo), "=&v"((U).h.hi) : "v"(ADDR))

#define LGKM_FENCE() do { \
    asm volatile("s_waitcnt lgkmcnt(0)" ::: "memory"); \
    __builtin_amdgcn_sched_barrier(0); } while (0)

// B staging slot for flat index s (0..511): thread writes 4 n-consecutive elems of row k.
__device__ inline void b_slot(int s, int* k, int* nq, int* off) {
    *k  = s >> 4;            // 0..31
    *nq = s & 15;            // n quad 0..15 (64 cols)
    *off = ((*nq) >> 2) * 1024 + ((*k) >> 2) * 128 + ((*k) & 3) * 32 + ((*nq) & 3) * 8;
}

// ---------------- router / bookkeeping (unchanged, validated) ----------------

__global__ __launch_bounds__(256) void router_kernel(
    const float* __restrict__ x, const float* __restrict__ rw,
    float* __restrict__ scores_out, int* __restrict__ eidx,
    float* __restrict__ score, int* __restrict__ counts, int T, int H, int E)
{
    int g = blockIdx.x * 256 + threadIdx.x;
    int t = g >> 3, e = g & 7;          // E == 8
    if (t >= T) return;
    const float* xr = x + (size_t)t * H;
    float acc = 0.f;
    for (int k = 0; k < H; k++) acc = fmaf(xr[k], rw[k * E + e], acc);
    float bv = acc; int bi = e;
    #pragma unroll
    for (int off = 4; off; off >>= 1) {
        float ov = __shfl_xor(bv, off, 8);
        int   oi = __shfl_xor(bi, off, 8);
        if (ov > bv || (ov == bv && oi < bi)) { bv = ov; bi = oi; }
    }
    float sig = 1.f / (1.f + __expf(-bv));
    scores_out[(size_t)e * T + t] = (e == bi) ? sig : 0.f;
    if (e == 0) {
        eidx[t] = bi;
        score[t] = sig;
        atomicAdd(&counts[bi], 1);
    }
}

__global__ void prefix_kernel(const int* __restrict__ counts, int* __restrict__ offs,
                              int* __restrict__ tile_e, int* __restrict__ tile_m,
                              int* __restrict__ ntile, int E)
{
    if (blockIdx.x == 0 && threadIdx.x == 0) {
        int run = 0, nt = 0;
        for (int e = 0; e < E; e++) {
            offs[e] = run;
            int c = counts[e];
            int t = (c + BM - 1) / BM;
            for (int i = 0; i < t; i++) { tile_e[nt] = e; tile_m[nt] = i * BM; nt++; }
            run += t * BM;
        }
        ntile[0] = nt;
    }
}

__global__ __launch_bounds__(256) void scatter_kernel(
    const int* __restrict__ eidx, const int* __restrict__ offs,
    int* __restrict__ cursor, int* __restrict__ list, int T)
{
    int t = blockIdx.x * 256 + threadIdx.x;
    if (t >= T) return;
    int e = eidx[t];
    int pos = offs[e] + atomicAdd(&cursor[e], 1);
    list[pos] = t;
}

// ---------------- shared expert up (gate+up, fused SwiGLU) ----------------

__global__ __launch_bounds__(256, 3) void shared_up(
    const float* __restrict__ X, const float* __restrict__ Wg,
    const float* __restrict__ Wu, unsigned short* __restrict__ Hout,
    int H, int I)
{
    __shared__ __attribute__((aligned(16)))  short As[BM][LDPA];
    __shared__ __attribute__((aligned(128))) char Bsh[2 * BMAT];
    const int tid = threadIdx.x;
    const int lane = tid & 63, wid = tid >> 6;
    const int wr = wid >> 1, wc = wid & 1;
    const int m0 = blockIdx.y * BM, n0 = blockIdx.x * BN;

    // A: thread -> row tid>>1, 16-k half (tid&1); 64B contiguous load
    const int am = tid >> 1, ak = (tid & 1) * 16;
    const float* apA = X + (size_t)(m0 + am) * H + ak;
    short* adst = &As[am][ak];

    char* bgd[2];
    const float *gsrc[2], *usrc[2];
#pragma unroll
    for (int p = 0; p < 2; p++) {
        int k, nq, off;
        b_slot(tid + p * 256, &k, &nq, &off);
        bgd[p] = Bsh + off;
        gsrc[p] = Wg + (size_t)k * I + (n0 + 4 * nq);
        usrc[p] = Wu + (size_t)k * I + (n0 + 4 * nq);
    }
    const int btr = (int)(size_t)Bsh + wc * 2048 + (lane >> 4) * 256 + 8 * (lane & 15);

    f32x4 accg[4][2], accu[4][2];
#pragma unroll
    for (int i = 0; i < 4; i++)
#pragma unroll
        for (int j = 0; j < 2; j++) {
            accg[i][j] = (f32x4){0.f, 0.f, 0.f, 0.f};
            accu[i][j] = (f32x4){0.f, 0.f, 0.f, 0.f};
        }

    float4 va[4], vg[2], vu[2];
#pragma unroll
    for (int q = 0; q < 4; q++) va[q] = *(const float4*)(apA + q * 4);
#pragma unroll
    for (int p = 0; p < 2; p++) { vg[p] = *(const float4*)gsrc[p]; vu[p] = *(const float4*)usrc[p]; }

    const int nK = H / BK;
    const int kh = (lane >> 4) * 8;
    for (int kt = 0; kt < nK; kt++) {
        __syncthreads();
        *(bf16x8*)adst       = pk8(va[0], va[1]);
        *(bf16x8*)(adst + 8) = pk8(va[2], va[3]);
#pragma unroll
        for (int p = 0; p < 2; p++) {
            *(unsigned long long*)bgd[p]          = pk4(vg[p]);
            *(unsigned long long*)(bgd[p] + BMAT) = pk4(vu[p]);
        }
        __syncthreads();
        if (kt + 1 < nK) {
            const int k0 = (kt + 1) * BK;
#pragma unroll
            for (int q = 0; q < 4; q++) va[q] = *(const float4*)(apA + k0 + q * 4);
#pragma unroll
            for (int p = 0; p < 2; p++) {
                vg[p] = *(const float4*)(gsrc[p] + (size_t)k0 * I);
                vu[p] = *(const float4*)(usrc[p] + (size_t)k0 * I);
            }
        }
        bf16x8 af[4];
#pragma unroll
        for (int q = 0; q < 4; q++)
            af[q] = *(const bf16x8*)&As[wr * 64 + q * 16 + (lane & 15)][kh];
        B8 gf[2], uf[2];
        TR8(gf[0], btr, "0",    "128");
        TR8(gf[1], btr, "1024", "1152");
        TR8(uf[0], btr, "4096", "4224");
        TR8(uf[1], btr, "5120", "5248");
        LGKM_FENCE();
#pragma unroll
        for (int mi = 0; mi < 4; mi++)
#pragma unroll
            for (int nj = 0; nj < 2; nj++) {
                accg[mi][nj] = __builtin_amdgcn_mfma_f32_16x16x32_bf16(af[mi], gf[nj].v, accg[mi][nj], 0, 0, 0);
                accu[mi][nj] = __builtin_amdgcn_mfma_f32_16x16x32_bf16(af[mi], uf[nj].v, accu[mi][nj], 0, 0, 0);
            }
    }

    const int rb = (lane >> 4) * 4, cb = lane & 15;
#pragma unroll
    for (int mi = 0; mi < 4; mi++)
#pragma unroll
        for (int nj = 0; nj < 2; nj++) {
            int col = n0 + wc * 32 + nj * 16 + cb;
#pragma unroll
            for (int j = 0; j < 4; j++) {
                float g = accg[mi][nj][j], u = accu[mi][nj][j];
                float r = u * g * __builtin_amdgcn_rcpf(1.f + __expf(-g));
                int row = m0 + wr * 64 + mi * 16 + rb + j;
                Hout[(size_t)row * I + col] = f2bf(r);
            }
        }
}

// ---------------- routed experts up (gathered + score-scaled A) ----------------

__global__ __launch_bounds__(256, 3) void routed_up(
    const float* __restrict__ X, const float* __restrict__ GUP,
    const int* __restrict__ counts, const int* __restrict__ offs,
    const int* __restrict__ list, const float* __restrict__ score,
    const int* __restrict__ tile_e, const int* __restrict__ tile_m,
    const int* __restrict__ ntile,
    unsigned short* __restrict__ Hout, int H, int I)
{
    const int gt = blockIdx.y;
    if (gt >= ntile[0]) return;
    const int e = tile_e[gt], mbase = tile_m[gt];
    const int count = counts[e], off_e = offs[e];
    const float* W = GUP + (size_t)e * H * (2 * I);
    const size_t ldw = 2 * (size_t)I;

    __shared__ __attribute__((aligned(16)))  short As[BM][LDPA];
    __shared__ __attribute__((aligned(128))) char Bsh[2 * BMAT];
    const int tid = threadIdx.x;
    const int lane = tid & 63, wid = tid >> 6;
    const int wr = wid >> 1, wc = wid & 1;
    const int n0 = blockIdx.x * BN;

    const int am = tid >> 1, ak = (tid & 1) * 16;
    int gr = mbase + am;
    int tok = 0; float sA = 0.f;
    if (gr < count) { tok = list[off_e + gr]; sA = score[tok]; }
    const float* apA = X + (size_t)tok * H + ak;
    short* adst = &As[am][ak];

    char* bgd[2];
    const float *gsrc[2], *usrc[2];
#pragma unroll
    for (int p = 0; p < 2; p++) {
        int k, nq, off;
        b_slot(tid + p * 256, &k, &nq, &off);
        bgd[p] = Bsh + off;
        gsrc[p] = W + (size_t)k * ldw + (n0 + 4 * nq);
        usrc[p] = gsrc[p] + I;
    }
    const int btr = (int)(size_t)Bsh + wc * 2048 + (lane >> 4) * 256 + 8 * (lane & 15);

    f32x4 accg[4][2], accu[4][2];
#pragma unroll
    for (int i = 0; i < 4; i++)
#pragma unroll
        for (int j = 0; j < 2; j++) {
            accg[i][j] = (f32x4){0.f, 0.f, 0.f, 0.f};
            accu[i][j] = (f32x4){0.f, 0.f, 0.f, 0.f};
        }

    float4 va[4], vg[2], vu[2];
#pragma unroll
    for (int q = 0; q < 4; q++) va[q] = *(const float4*)(apA + q * 4);
#pragma unroll
    for (int p = 0; p < 2; p++) { vg[p] = *(const float4*)gsrc[p]; vu[p] = *(const float4*)usrc[p]; }

    const int nK = H / BK;
    const int kh = (lane >> 4) * 8;
    for (int kt = 0; kt < nK; kt++) {
        __syncthreads();
        {
            float4 s0 = make_float4(va[0].x * sA, va[0].y * sA, va[0].z * sA, va[0].w * sA);
            float4 s1 = make_float4(va[1].x * sA, va[1].y * sA, va[1].z * sA, va[1].w * sA);
            float4 s2 = make_float4(va[2].x * sA, va[2].y * sA, va[2].z * sA, va[2].w * sA);
            float4 s3 = make_float4(va[3].x * sA, va[3].y * sA, va[3].z * sA, va[3].w * sA);
            *(bf16x8*)adst       = pk8(s0, s1);
            *(bf16x8*)(adst + 8) = pk8(s2, s3);
        }
#pragma unroll
        for (int p = 0; p < 2; p++) {
            *(unsigned long long*)bgd[p]          = pk4(vg[p]);
            *(unsigned long long*)(bgd[p] + BMAT) = pk4(vu[p]);
        }
        __syncthreads();
        if (kt + 1 < nK) {
            const int k0 = (kt + 1) * BK;
#pragma unroll
            for (int q = 0; q < 4; q++) va[q] = *(const float4*)(apA + k0 + q * 4);
#pragma unroll
            for (int p = 0; p < 2; p++) {
                vg[p] = *(const float4*)(gsrc[p] + (size_t)k0 * ldw);
                vu[p] = *(const float4*)(usrc[p] + (size_t)k0 * ldw);
            }
        }
        bf16x8 af[4];
#pragma unroll
        for (int q = 0; q < 4; q++)
            af[q] = *(const bf16x8*)&As[wr * 64 + q * 16 + (lane & 15)][kh];
        B8 gf[2], uf[2];
        TR8(gf[0], btr, "0",    "128");
        TR8(gf[1], btr, "1024", "1152");
        TR8(uf[0], btr, "4096", "4224");
        TR8(uf[1], btr, "5120", "5248");
        LGKM_FENCE();
#pragma unroll
        for (int mi = 0; mi < 4; mi++)
#pragma unroll
            for (int nj = 0; nj < 2; nj++) {
                accg[mi][nj] = __builtin_amdgcn_mfma_f32_16x16x32_bf16(af[mi], gf[nj].v, accg[mi][nj], 0, 0, 0);
                accu[mi][nj] = __builtin_amdgcn_mfma_f32_16x16x32_bf16(af[mi], uf[nj].v, accu[mi][nj], 0, 0, 0);
            }
    }

    const int rb = (lane >> 4) * 4, cb = lane & 15;
#pragma unroll
    for (int mi = 0; mi < 4; mi++)
#pragma unroll
        for (int nj = 0; nj < 2; nj++) {
            int col = n0 + wc * 32 + nj * 16 + cb;
#pragma unroll
            for (int j = 0; j < 4; j++) {
                float g = accg[mi][nj][j], u = accu[mi][nj][j];
                float r = u * g * __builtin_amdgcn_rcpf(1.f + __expf(-g));
                int row = off_e + mbase + wr * 64 + mi * 16 + rb + j;
                Hout[(size_t)row * I + col] = f2bf(r);
            }
        }
}

// ---------------- fused down: out[tok] = SH[tok]@Wsd + RH[slot]@Dp_e ----------------

__global__ __launch_bounds__(256, 3) void fused_down(
    const unsigned short* __restrict__ SH, const unsigned short* __restrict__ RH,
    const float* __restrict__ Wsd, const float* __restrict__ DP,
    const int* __restrict__ counts, const int* __restrict__ offs,
    const int* __restrict__ list,
    const int* __restrict__ tile_e, const int* __restrict__ tile_m,
    const int* __restrict__ ntile,
    float* __restrict__ out, int I, int H)
{
    const int gt = blockIdx.y;
    if (gt >= ntile[0]) return;
    const int e = tile_e[gt], mbase = tile_m[gt];
    const int count = counts[e], off_e = offs[e];
    const float* W2 = DP + (size_t)e * I * H;

    __shared__ __attribute__((aligned(16)))  short A1[BM][LDPA], A2[BM][LDPA];
    __shared__ __attribute__((aligned(128))) char Bsh[2 * BMAT];
    __shared__ int toks[BM];
    const int tid = threadIdx.x;
    const int lane = tid & 63, wid = tid >> 6;
    const int wr = wid >> 1, wc = wid & 1;
    const int n0 = blockIdx.x * BN;

    if (tid < BM) {
        int gr = mbase + tid;
        toks[tid] = (gr < count) ? list[off_e + gr] : -1;
    }
    __syncthreads();

    const int am = tid >> 1, ak = (tid & 1) * 16;
    int tokA = toks[am]; if (tokA < 0) tokA = 0;
    const unsigned short* a1p = SH + (size_t)tokA * I + ak;
    const unsigned short* a2p = RH + (size_t)(off_e + mbase + am) * I + ak;
    short* a1d = &A1[am][ak];
    short* a2d = &A2[am][ak];

    char* b1d[2];
    const float *b1s[2], *b2s[2];
#pragma unroll
    for (int p = 0; p < 2; p++) {
        int k, nq, off;
        b_slot(tid + p * 256, &k, &nq, &off);
        b1d[p] = Bsh + off;
        b1s[p] = Wsd + (size_t)k * H + (n0 + 4 * nq);
        b2s[p] = W2  + (size_t)k * H + (n0 + 4 * nq);
    }
    const int btr = (int)(size_t)Bsh + wc * 2048 + (lane >> 4) * 256 + 8 * (lane & 15);

    f32x4 acc[4][2];
#pragma unroll
    for (int i = 0; i < 4; i++)
#pragma unroll
        for (int j = 0; j < 2; j++) acc[i][j] = (f32x4){0.f, 0.f, 0.f, 0.f};

    bf16x8 w1[2], w2[2];
    float4 vb1[2], vb2[2];
    w1[0] = *(const bf16x8*)a1p; w1[1] = *(const bf16x8*)(a1p + 8);
    w2[0] = *(const bf16x8*)a2p; w2[1] = *(const bf16x8*)(a2p + 8);
#pragma unroll
    for (int p = 0; p < 2; p++) { vb1[p] = *(const float4*)b1s[p]; vb2[p] = *(const float4*)b2s[p]; }

    const int nK = I / BK;
    const int kh = (lane >> 4) * 8;
    for (int kt = 0; kt < nK; kt++) {
        __syncthreads();
        *(bf16x8*)a1d       = w1[0];
        *(bf16x8*)(a1d + 8) = w1[1];
        *(bf16x8*)a2d       = w2[0];
        *(bf16x8*)(a2d + 8) = w2[1];
#pragma unroll
        for (int p = 0; p < 2; p++) {
            *(unsigned long long*)b1d[p]          = pk4(vb1[p]);
            *(unsigned long long*)(b1d[p] + BMAT) = pk4(vb2[p]);
        }
        __syncthreads();
        if (kt + 1 < nK) {
            const int k0 = (kt + 1) * BK;
            w1[0] = *(const bf16x8*)(a1p + k0); w1[1] = *(const bf16x8*)(a1p + k0 + 8);
            w2[0] = *(const bf16x8*)(a2p + k0); w2[1] = *(const bf16x8*)(a2p + k0 + 8);
#pragma unroll
            for (int p = 0; p < 2; p++) {
                vb1[p] = *(const float4*)(b1s[p] + (size_t)k0 * H);
                vb2[p] = *(const float4*)(b2s[p] + (size_t)k0 * H);
            }
        }
        bf16x8 af1[4], af2[4];
#pragma unroll
        for (int q = 0; q < 4; q++) {
            af1[q] = *(const bf16x8*)&A1[wr * 64 + q * 16 + (lane & 15)][kh];
            af2[q] = *(const bf16x8*)&A2[wr * 64 + q * 16 + (lane & 15)][kh];
        }
        B8 b1f[2], b2f[2];
        TR8(b1f[0], btr, "0",    "128");
        TR8(b1f[1], btr, "1024", "1152");
        TR8(b2f[0], btr, "4096", "4224");
        TR8(b2f[1], btr, "5120", "5248");
        LGKM_FENCE();
#pragma unroll
        for (int mi = 0; mi < 4; mi++)
#pragma unroll
            for (int nj = 0; nj < 2; nj++) {
                acc[mi][nj] = __builtin_amdgcn_mfma_f32_16x16x32_bf16(af1[mi], b1f[nj].v, acc[mi][nj], 0, 0, 0);
                acc[mi][nj] = __builtin_amdgcn_mfma_f32_16x16x32_bf16(af2[mi], b2f[nj].v, acc[mi][nj], 0, 0, 0);
            }
    }

    const int rb = (lane >> 4) * 4, cb = lane & 15;
#pragma unroll
    for (int mi = 0; mi < 4; mi++)
#pragma unroll
        for (int nj = 0; nj < 2; nj++) {
            int col = n0 + wc * 32 + nj * 16 + cb;
#pragma unroll
            for (int j = 0; j < 4; j++) {
                int lr = wr * 64 + mi * 16 + rb + j;
                int tok = toks[lr];
                if (tok >= 0) out[(size_t)tok * H + col] = acc[mi][nj][j];
            }
        }
}

// ---------------- launcher ----------------

extern "C" void kernel_launch(void* const* d_in, const int* in_sizes, int n_in,
                              void* d_out, int out_size, void* d_ws, size_t ws_size,
                              hipStream_t stream)
{
    const float* x   = (const float*)d_in[0];
    const float* rw  = (const float*)d_in[1];
    const float* gup = (const float*)d_in[2];
    const float* dp  = (const float*)d_in[3];
    const float* sg  = (const float*)d_in[4];
    const float* su  = (const float*)d_in[5];
    const float* sd  = (const float*)d_in[6];

    const int H = 2048, I = 4096, E = 8;
    const int T = in_sizes[0] / H;            // 2048

    float* out        = (float*)d_out;
    float* scores_out = out + (size_t)T * H;  // router_scores [E, T]

    const int slotsCap = T + E * BM;          // 3072
    unsigned short* routedH = (unsigned short*)d_ws;                  // [slotsCap, I] bf16
    unsigned short* sharedH = routedH + (size_t)slotsCap * I;         // [T, I] bf16
    int*   list   = (int*)(sharedH + (size_t)T * I);                  // [slotsCap]
    int*   eidx   = list + slotsCap;                                  // [T]
    float* score  = (float*)(eidx + T);                               // [T]
    int*   counts = (int*)(score + T);                                // [E]
    int*   cursor = counts + E;                                       // [E]
    int*   offs   = cursor + E;                                       // [E]
    int*   ntile  = offs + E;                                         // [1]
    int*   tile_e = ntile + 1;                                        // [MAXT]
    int*   tile_m = tile_e + MAXT;                                    // [MAXT]

    const int maxTiles = T / BM + E;          // 24 (>= worst-case padded tile count)

    hipMemsetAsync(counts, 0, 2 * E * sizeof(int), stream);
    router_kernel<<<(T * E) / 256, 256, 0, stream>>>(x, rw, scores_out, eidx, score, counts, T, H, E);
    prefix_kernel<<<1, 1, 0, stream>>>(counts, offs, tile_e, tile_m, ntile, E);
    scatter_kernel<<<(T + 255) / 256, 256, 0, stream>>>(eidx, offs, cursor, list, T);
    shared_up<<<dim3(I / BN, T / BM), 256, 0, stream>>>(x, sg, su, sharedH, H, I);
    routed_up<<<dim3(I / BN, maxTiles), 256, 0, stream>>>(x, gup, counts, offs, list, score,
                                                          tile_e, tile_m, ntile, routedH, H, I);
    fused_down<<<dim3(H / BN, maxTiles), 256, 0, stream>>>(sharedH, routedH, sd, dp,
                                                           counts, offs, list,
                                                           tile_e, tile_m, ntile, out, I, H);
}